// Round 9
// baseline (414.632 us; speedup 1.0000x reference)
//
#include <hip/hip_runtime.h>
#include <cstdint>
#include <cstddef>

#define NV 50000
#define ED 128
#define SS 50
#define NB 128
#define NM 200
#define BMD (NB*NM*ED)   // 3,276,800 floats per table
#define NCH 32
#define CHD 1563         // ceil(50000/32)

typedef _Float16 f16x8 __attribute__((ext_vector_type(8)));
typedef _Float16 f16x4 __attribute__((ext_vector_type(4)));
typedef float    f32x4 __attribute__((ext_vector_type(4)));

// ---------------------------------------------------------------------------
// Kernel A: vocab-chunked gather-reduce (gather part unchanged — ~92% of the
// ~3.4 TB/s miss-path roofline, FETCH at the 8-XCD compulsory floor) + fused
// C3 fp32->f16 conversion (4096 floats/block; hides the former cvt kernel).
// ---------------------------------------------------------------------------
__global__ __launch_bounds__(256) void story_embed_k(
    const int* __restrict__ story, const float* __restrict__ C,
    float* __restrict__ Mt, _Float16* __restrict__ C3h) {
  // ---- fused C3 -> f16 (coalesced float4 loads / f16x4 stores)
  {
    const float* C3 = C + (size_t)3 * NV * ED;
    const int base4 = blockIdx.x * 1024;       // float4 groups per block
#pragma unroll
    for (int r = 0; r < 4; ++r) {
      int i4 = base4 + r * 256 + threadIdx.x;
      if (i4 < NV * ED / 4) {
        float4 f = ((const float4*)C3)[i4];
        f16x4 h;
        h[0] = (_Float16)f.x; h[1] = (_Float16)f.y;
        h[2] = (_Float16)f.z; h[3] = (_Float16)f.w;
        *(f16x4*)(C3h + (size_t)4 * i4) = h;
      }
    }
  }

  const int wave = threadIdx.x >> 6;
  const int lane = threadIdx.x & 63;
  const int bm0 = blockIdx.x * 16;
  const int sl = (lane < SS) ? lane : (SS - 1);

  int idxg[4], cidg[4];
#pragma unroll
  for (int gg = 0; gg < 4; ++gg) {
    const int bm = bm0 + wave + 4 * gg;
    idxg[gg] = story[(size_t)bm * SS + sl];
    cidg[gg] = (lane < SS) ? (idxg[gg] / CHD) : -1;
  }
  const float a0 = ((float)(2*lane + 1) - 64.5f) * 6.25e-4f;
  const float a1 = ((float)(2*lane + 2) - 64.5f) * 6.25e-4f;
  float2 acc[4][4];
#pragma unroll
  for (int gg = 0; gg < 4; ++gg)
#pragma unroll
    for (int k = 0; k < 4; ++k) acc[gg][k] = make_float2(0.f, 0.f);

  for (int c = 0; c < NCH; ++c) {
#pragma unroll
    for (int gg = 0; gg < 4; ++gg) {
      unsigned long long mask = __ballot(cidg[gg] == c);
      while (mask) {
        const int s = __builtin_ctzll(mask);
        mask &= mask - 1;
        const int row = __shfl(idxg[gg], s);
        float e0, e1;
        if (s == SS - 1) { e0 = 1.0f; e1 = 1.0f; }
        else {
          float js = (float)(s + 1) - 25.5f;
          e0 = fmaf(a0, js, 1.0f);
          e1 = fmaf(a1, js, 1.0f);
        }
        const float* base = C + (size_t)row * ED + 2 * lane;
#pragma unroll
        for (int k = 0; k < 4; ++k) {
          float2 cv = *(const float2*)(base + (size_t)k * NV * ED);
          acc[gg][k].x = fmaf(e0, cv.x, acc[gg][k].x);
          acc[gg][k].y = fmaf(e1, cv.y, acc[gg][k].y);
        }
      }
    }
    __syncthreads();
  }

#pragma unroll
  for (int gg = 0; gg < 4; ++gg) {
    const int bm = bm0 + wave + 4 * gg;
#pragma unroll
    for (int k = 0; k < 4; ++k)
      *(float2*)(Mt + (size_t)k * BMD + (size_t)bm * ED + 2 * lane) = acc[gg][k];
  }
}

// ---------------------------------------------------------------------------
// Kernel B (v3): per-batch hop loop, ZERO staging. 512 thr/block, 1 block/b.
// Scores and o read Mt straight from global (coalesced 512B/wave float2 and
// 256B/instr strided-d loads). MC of hop h is re-read as MA of hop h+1 from
// a hot L2 — the LDS tile's reuse without the tile. No big register arrays,
// no launch_bounds cap, ~3 KB LDS, <80 VGPRs.
// ---------------------------------------------------------------------------
__global__ __launch_bounds__(512) void hops_k(
    const int* __restrict__ query, const float* __restrict__ C,
    const float* __restrict__ Tw, const float* __restrict__ Tb,
    const float* __restrict__ Mt, float* __restrict__ U) {
  const int b = blockIdx.x;
  const int tid = threadIdx.x;                   // 0..511
  const int d = tid & 127;
  const int p = tid >> 7;                        // 0..3
  const int wave = tid >> 6, lane = tid & 63;
  __shared__ float u[ED];
  __shared__ float part[512];
  __shared__ float sc[NM];
  __shared__ float o[ED];

  // ---- u0 = sum_s enc[s][d] * C0[query[b][s]][d]
  {
    const float ad = ((float)(d + 1) - 64.5f) * 6.25e-4f;
    int rows[13];
#pragma unroll
    for (int j = 0; j < 13; ++j) {
      int s = p + 4 * j;
      rows[j] = query[b * SS + (s < SS ? s : 0)];
    }
    float cv[13];
#pragma unroll
    for (int j = 0; j < 13; ++j)
      cv[j] = C[(size_t)rows[j] * ED + d];
    float accv = 0.f;
#pragma unroll
    for (int j = 0; j < 13; ++j) {
      int s = p + 4 * j;
      float e;
      if (s >= SS) e = 0.f;
      else if (s == SS - 1) e = 1.0f;
      else e = fmaf(ad, (float)(s + 1) - 25.5f, 1.0f);
      accv = fmaf(e, cv[j], accv);
    }
    part[tid] = accv;
  }
  __syncthreads();
  if (tid < ED)
    u[tid] = part[tid] + part[tid + 128] + part[tid + 256] + part[tid + 384];
  __syncthreads();

  for (int hop = 0; hop < 3; ++hop) {
    const float* MA = Mt + (size_t)hop * BMD + (size_t)b * NM * ED;
    const float* MC = MA + BMD;                  // table k = hop+1

    // ---- scores[m] = dot(MA[m], u) — 4 rows in flight per wave
    {
      float u0v = u[2 * lane], u1v = u[2 * lane + 1];
      for (int m = wave; m < NM; m += 32) {
        float pa[4] = {0.f, 0.f, 0.f, 0.f};
#pragma unroll
        for (int t = 0; t < 4; ++t) {
          int mm = m + 8 * t;
          if (mm < NM) {
            float2 r = *(const float2*)(MA + (size_t)mm * ED + 2 * lane);
            pa[t] = r.x * u0v + r.y * u1v;
          }
        }
#pragma unroll
        for (int off = 32; off; off >>= 1) {
#pragma unroll
          for (int t = 0; t < 4; ++t) pa[t] += __shfl_xor(pa[t], off);
        }
        if (lane == 0) {
#pragma unroll
          for (int t = 0; t < 4; ++t) {
            int mm = m + 8 * t;
            if (mm < NM) sc[mm] = pa[t];
          }
        }
      }
    }
    __syncthreads();

    // ---- softmax (wave shfl reductions)
    float v = (tid < NM) ? sc[tid] : -1e30f;
    {
      float t = v;
#pragma unroll
      for (int off = 32; off; off >>= 1) t = fmaxf(t, __shfl_xor(t, off));
      if (lane == 0) part[wave] = t;
    }
    __syncthreads();
    float mx = part[0];
#pragma unroll
    for (int w = 1; w < 8; ++w) mx = fmaxf(mx, part[w]);
    float ev = 0.f;
    if (tid < NM) { ev = __expf(v - mx); sc[tid] = ev; }
    {
      float t = ev;
#pragma unroll
      for (int off = 32; off; off >>= 1) t += __shfl_xor(t, off);
      if (lane == 0) part[8 + wave] = t;
    }
    __syncthreads();
    float tot = part[8];
#pragma unroll
    for (int w = 9; w < 16; ++w) tot += part[w];
    const float inv = 1.0f / tot;
    __syncthreads();

    // ---- o[d] = (sum_m sc[m] * MC[m][d]) * inv — direct global, 5x10 regs
    {
      float oacc = 0.f;
#pragma unroll
      for (int jb = 0; jb < 5; ++jb) {
        float vbuf[10];
#pragma unroll
        for (int j = 0; j < 10; ++j)
          vbuf[j] = MC[(size_t)(p + 4 * (jb * 10 + j)) * ED + d];
#pragma unroll
        for (int j = 0; j < 10; ++j)
          oacc = fmaf(sc[p + 4 * (jb * 10 + j)], vbuf[j], oacc);
      }
      part[tid] = oacc;
    }
    __syncthreads();
    if (tid < ED)
      o[tid] = (part[tid] + part[tid + 128] + part[tid + 256] + part[tid + 384])
               * inv;
    __syncthreads();

    // ---- t = sigmoid(u @ Tw^T + Tb); u = (1-t)*u + o*t
    {
      const float4* twr = (const float4*)(Tw + (size_t)d * ED + p * 32);
      float4 tw4[8];
#pragma unroll
      for (int j = 0; j < 8; ++j) tw4[j] = twr[j];
      float tacc = 0.f;
#pragma unroll
      for (int j = 0; j < 8; ++j) {
        tacc = fmaf(u[p * 32 + 4 * j + 0], tw4[j].x, tacc);
        tacc = fmaf(u[p * 32 + 4 * j + 1], tw4[j].y, tacc);
        tacc = fmaf(u[p * 32 + 4 * j + 2], tw4[j].z, tacc);
        tacc = fmaf(u[p * 32 + 4 * j + 3], tw4[j].w, tacc);
      }
      part[tid] = tacc;
    }
    __syncthreads();
    if (tid < ED) {
      float dot = part[tid] + part[tid + 128] + part[tid + 256] + part[tid + 384]
                  + Tb[tid];
      float tk = 1.0f / (1.0f + __expf(-dot));
      u[tid] = (1.0f - tk) * u[tid] + o[tid] * tk;
    }
    __syncthreads();
  }
  if (tid < ED) U[(size_t)b * ED + tid] = u[tid];
}

// ---------------------------------------------------------------------------
// Kernel C: a_hat = U @ C3^T via f16 MFMA (fp32 accumulate) — unchanged r8.
// ---------------------------------------------------------------------------
__global__ __launch_bounds__(256) void out_mm_mfma_k(
    const float* __restrict__ U, const _Float16* __restrict__ C3h,
    float* __restrict__ out) {
  __shared__ _Float16 Ub[ED * 136];   // 34,816 B
  const int tid = threadIdx.x;

  {
    const float4* u4 = (const float4*)U;
#pragma unroll
    for (int j = 0; j < 16; ++j) {
      int i = tid + 256 * j;
      float4 f = u4[i];
      int row = i >> 5;
      int col = (i & 31) * 4;
      f16x4 h;
      h[0] = (_Float16)f.x; h[1] = (_Float16)f.y;
      h[2] = (_Float16)f.z; h[3] = (_Float16)f.w;
      *(f16x4*)&Ub[row * 136 + col] = h;
    }
  }
  __syncthreads();

  const int wave = tid >> 6, lane = tid & 63;
  const int n = lane & 15, q = lane >> 4;
  const int v = blockIdx.x * 64 + wave * 16 + n;
  const bool vok = (v < NV);

  f32x4 acc[8];
#pragma unroll
  for (int mt = 0; mt < 8; ++mt) acc[mt] = (f32x4){0.f, 0.f, 0.f, 0.f};

#pragma unroll
  for (int kt = 0; kt < 4; ++kt) {
    f16x8 bfrag = {};
    if (vok) bfrag = *(const f16x8*)(C3h + (size_t)v * ED + kt * 32 + q * 8);
#pragma unroll
    for (int mt = 0; mt < 8; ++mt) {
      f16x8 afrag = *(const f16x8*)&Ub[(mt * 16 + n) * 136 + kt * 32 + q * 8];
      acc[mt] = __builtin_amdgcn_mfma_f32_16x16x32_f16(afrag, bfrag, acc[mt],
                                                       0, 0, 0);
    }
  }

  if (vok) {
#pragma unroll
    for (int mt = 0; mt < 8; ++mt)
#pragma unroll
      for (int i = 0; i < 4; ++i)
        out[(size_t)(mt * 16 + q * 4 + i) * NV + v] = acc[mt][i];
  }
}

// ---------------------------------------------------------------------------
extern "C" void kernel_launch(void* const* d_in, const int* in_sizes, int n_in,
                              void* d_out, int out_size, void* d_ws, size_t ws_size,
                              hipStream_t stream) {
  const int*   story = (const int*)d_in[0];   // [128,200,50]
  const int*   query = (const int*)d_in[1];   // [128,50]
  const float* C     = (const float*)d_in[2]; // [4,50000,128]
  const float* Tw    = (const float*)d_in[3]; // [128,128]
  const float* Tb    = (const float*)d_in[4]; // [128]
  float* out = (float*)d_out;                 // [128,50000]

  float* wsf = (float*)d_ws;
  float*     Mt  = wsf;                                   // 4*BMD floats
  float*     U   = wsf + (size_t)4 * BMD;                 // 16384 floats
  _Float16*  C3h = (_Float16*)(wsf + (size_t)4 * BMD + NB * ED);

  hipLaunchKernelGGL(story_embed_k, dim3(NB * NM / 16), dim3(256), 0, stream,
                     story, C, Mt, C3h);
  hipLaunchKernelGGL(hops_k, dim3(NB), dim3(512), 0, stream,
                     query, C, Tw, Tb, Mt, U);
  hipLaunchKernelGGL(out_mm_mfma_k, dim3((NV + 63) / 64), dim3(256), 0, stream,
                     U, C3h, out);
}